// Round 7
// baseline (372.732 us; speedup 1.0000x reference)
//
#include <hip/hip_runtime.h>
#include <hip/hip_bf16.h>

#define CIN 32
#define OCH 64
#define HH  256
#define WW  256
#define HW  (HH * WW)
#define BH  8                 // output rows per wave-tile
#define SLOTB (34 * 64)       // 34 w-entries x 64B = 2176 B per row-slot
#define RINGB (4 * SLOTB)     // private 4-slot ring per wave

typedef __bf16 bf16x8 __attribute__((ext_vector_type(8)));
typedef float  f32x16 __attribute__((ext_vector_type(16)));

// Barrier-free wave-private fused 3x3 conv, 32x32x16 bf16 MFMA.
// Each wave owns (b, 8-row h-tile, 32-w tile, 32-o half) and stages its own
// 34-entry LDS row ring (no cross-wave LDS sharing -> no __syncthreads at all).
// B-fragment read exactly once per (tap,kstep): 18 ds_read_b128/row/wave
// (vs 144 redundant in the o-split-by-4 design) -> LDS pipe off critical path.
// LDS w-entry (keyed GLOBAL w): 64B = 4 chunks of 8 ch; chunk sc stored at
// sc ^ ((w>>1)&3); reads verified uniform 8-touches/bank (conflict-free).
// A: lane row=l&31, k=(l>>5)*8+j (family analogy to verified 16x16x32).
// D: col=l&31, row=(reg&3)+8*(reg>>2)+4*(l>>5)  [m74/m101].
__global__ __launch_bounds__(256, 3) void conv_wave_kernel(
        const float* __restrict__ x, const float* __restrict__ wgt,
        const float* __restrict__ bias, float* __restrict__ out) {
    const int bid = blockIdx.x;                  // 0..2047
    const int nid = (bid & 7) * 256 + (bid >> 3);   // XCD-chunked swizzle
    const int tid = threadIdx.x;
    const int wid = tid >> 6, l = tid & 63;
    const int unit = nid * 2 + (wid >> 1);       // 0..4095 tile id
    const int og = wid & 1;                      // o-half (og0/og1 same tile ->
    const int wt = unit & 7;                     //  co-resident, L1-shared x)
    const int ht = (unit >> 3) & 31;
    const int b  = unit >> 8;
    const int w0 = wt * 32;
    const int h0 = ht * BH;
    const int lw = l & 31;
    const int hi = l >> 5;

    __shared__ char lds_all[4][RINGB];           // 34,816 B
    char* ring = &lds_all[wid][0];
    const float* xb = x + (size_t)b * CIN * HW;

    // ---- A fragments: af[tap][ks], o-row = og*32+lw, k = ks*16+hi*8+j
    bf16x8 af[9][2];
    {
        const float* wrow = wgt + (size_t)(og * 32 + lw) * 288 + hi * 8 * 9;
#pragma unroll
        for (int ks = 0; ks < 2; ++ks)
#pragma unroll
            for (int t = 0; t < 9; ++t)
#pragma unroll
                for (int j = 0; j < 8; ++j)
                    af[t][ks][j] = (__bf16)wrow[ks * 144 + j * 9 + t];
    }

    // staging lane map: 16 w-pairs x 4 ch-groups (main), 2 halo cols x 32 ch
    const int wp  = (l & 15) * 2;
    const int g   = l >> 4;
    const int wgh = w0 + (hi ? 32 : -1);         // halo col handled by lane
    const int chh = lw;                          // halo channel

    auto loadrow = [&](int row, float2 (&v)[8], float& hv) {
        if (row >= 0 && row < HH) {
            const float* rp = xb + (size_t)row * WW;
#pragma unroll
            for (int j = 0; j < 8; ++j)
                v[j] = *(const float2*)(rp + (size_t)(g * 8 + j) * HW + w0 + wp);
            hv = (wgh >= 0 && wgh < WW) ? rp[(size_t)chh * HW + wgh] : 0.f;
        } else {
#pragma unroll
            for (int j = 0; j < 8; ++j) v[j] = make_float2(0.f, 0.f);
            hv = 0.f;
        }
    };

    auto writerow = [&](int row, float2 (&v)[8], float hv) {
        char* slot = ring + ((row + 1) & 3) * SLOTB;
#pragma unroll
        for (int p = 0; p < 2; ++p) {
            const int wl = wp + p;
            const int wglob = w0 + wl;
            bf16x8 pk;
#pragma unroll
            for (int j = 0; j < 8; ++j) pk[j] = (__bf16)(p ? v[j].y : v[j].x);
            *(bf16x8*)(slot + (wl + 1) * 64 + ((g ^ ((wglob >> 1) & 3)) << 4)) = pk;
        }
        const int e  = hi ? 33 : 0;
        const int mh = (wgh < 0) ? 3 : ((wgh >> 1) & 3);
        *(__bf16*)(slot + e * 64 + (((chh >> 3) ^ mh) << 4) + (chh & 7) * 2) =
            (__bf16)hv;
    };

    // ---- prologue: rows h0-1..h0+1 staged; preload row h0+2 into vA
    {
        float2 t0[8]; float th;
        loadrow(h0 - 1, t0, th); writerow(h0 - 1, t0, th);
        loadrow(h0,     t0, th); writerow(h0,     t0, th);
        loadrow(h0 + 1, t0, th); writerow(h0 + 1, t0, th);
    }
    float2 vA[8], vB[8]; float hA = 0.f, hB = 0.f;
    loadrow(h0 + 2, vA, hA);

    // per-lane swizzled B-read offsets (wt*32 drops out of (u>>1)&3;
    // u<0 only at image left edge -> that 64B entry is zeroed anyway)
    int off6[3][2];
#pragma unroll
    for (int kw = 0; kw < 3; ++kw) {
        const int u = w0 + lw + kw - 1;
        const int m = (u < 0) ? 3 : ((u >> 1) & 3);
#pragma unroll
        for (int ks = 0; ks < 2; ++ks)
            off6[kw][ks] = (lw + kw) * 64 + (((ks * 2 + hi) ^ m) << 4);
    }

    const float* bp = bias + og * 32 + 4 * hi;
    float* ob = out + ((size_t)b * OCH + og * 32) * HW + (size_t)h0 * WW + w0 + lw;

    // body: compute output row h0+i; vprev holds row h+2 (written for next
    // iter), vnext receives row h+3 (written at iter i+1). 2-deep pipeline.
    auto body = [&](int i, float2 (&vprev)[8], float hprev,
                    float2 (&vnext)[8], float& hnext) {
        const int h = h0 + i;
        if (i < 6) loadrow(h + 3, vnext, hnext);   // issue-early (T14)

        f32x16 acc;
#pragma unroll
        for (int r = 0; r < 16; ++r) acc[r] = 0.f;
#pragma unroll
        for (int kh = 0; kh < 3; ++kh) {           // input rows h-1..h+1
            const char* s = ring + ((h + kh) & 3) * SLOTB;
#pragma unroll
            for (int ks = 0; ks < 2; ++ks)
#pragma unroll
                for (int kw = 0; kw < 3; ++kw) {
                    bf16x8 bf = *(const bf16x8*)(s + off6[kw][ks]);
                    acc = __builtin_amdgcn_mfma_f32_32x32x16_bf16(
                        af[kh * 3 + kw][ks], bf, acc, 0, 0, 0);
                }
        }

        if (i < 7) writerow(h + 2, vprev, hprev);  // write-late

        // stores: D col=lw, row=(r&3)+8*(r>>2)+4*hi; bias via L1-hot loads
        float* obr = ob + (size_t)i * WW;
#pragma unroll
        for (int r = 0; r < 16; ++r) {
            const int ro = (r & 3) + 8 * (r >> 2);
            obr[(size_t)(ro + 4 * hi) * HW] = acc[r] + bp[ro];
        }
    };

    for (int i2 = 0; i2 < 4; ++i2) {
        body(i2 * 2,     vA, hA, vB, hB);
        body(i2 * 2 + 1, vB, hB, vA, hA);
    }
}

extern "C" void kernel_launch(void* const* d_in, const int* in_sizes, int n_in,
                              void* d_out, int out_size, void* d_ws, size_t ws_size,
                              hipStream_t stream) {
    const float* x    = (const float*)d_in[0];
    const float* w    = (const float*)d_in[1];
    const float* bias = (const float*)d_in[2];
    float* out = (float*)d_out;

    hipLaunchKernelGGL(conv_wave_kernel, dim3(2048), dim3(256), 0, stream,
                       x, w, bias, out);
}

// Round 8
// 115.479 us; speedup vs baseline: 3.2277x; 3.2277x over previous
//
#include <hip/hip_runtime.h>
#include <hip/hip_bf16.h>

#define CIN 32
#define OCH 64
#define HH  256
#define WW  256
#define HW  (HH * WW)
#define BH  8                 // output rows per block
#define ROWB (258 * 64)       // 16512 B per LDS row-slot

typedef __bf16 bf16x8 __attribute__((ext_vector_type(8)));
typedef float  f32x4  __attribute__((ext_vector_type(4)));
typedef float  f32x16 __attribute__((ext_vector_type(16)));

// Fused 3x3 conv, r3 skeleton + 32x32x16 bf16 MFMA.
// Block = (b, 8-row h-tile), 4 waves; wave = (o-half og, w-half wf): 32 o x
// 128 w. 32x32 tiles double B-fragment o-reuse -> LDS B-read traffic halves
// vs r3 (each 1KiB wave-read feeds 32 o-rows). Staging identical to r3
// (cooperative full 256-w rows, 4-slot ring, global-w-keyed chunk swizzle).
// Fragment layouts validated end-to-end in r7 (passed absmax):
//   A: row=l&31, k=(l>>5)*8+j;  B: k=(l>>5)*8+j, col=l&31;
//   D: col=l&31, row=(r&3)+8*(r>>2)+4*(l>>5)   [m74/m101].
// launch_bounds(256,1): full 512-reg budget -> no allocator cap / no spill
// (r4/r5/r7 regression root-cause: spill traffic inflating FETCH/WRITE).
__global__ __launch_bounds__(256, 1) void conv_fused_kernel(
        const float* __restrict__ x, const float* __restrict__ wgt,
        const float* __restrict__ bias, float* __restrict__ out) {
    // chunked XCD swizzle: 512 blocks, 64 consecutive nids per XCD.
    const int bid = blockIdx.x;
    const int nid = (bid & 7) * 64 + (bid >> 3);
    const int b   = nid >> 5;                    // 0..15
    const int h0  = (nid & 31) * BH;             // 0..248
    const int tid = threadIdx.x;
    const int l   = tid & 63, wid = tid >> 6;
    const int lw  = l & 31,  hi  = l >> 5;
    const int og  = wid & 1;                     // o-half: o = og*32 + ...
    const int wf  = wid >> 1;                    // w-half: w = wf*128 + ...

    __shared__ __bf16 xs[4][258][CIN];           // 66,048 B ring of 4 row-slots
    char* lds = (char*)&xs[0][0][0];
    const float* xb = x + (size_t)b * CIN * HW;

    // zero the w-pad entries (wp=0 and wp=257) of all 4 slots
    if (tid < 32) {
        const int s = tid >> 3, k = tid & 7;
        const int wp = (k < 4) ? 0 : 257;
        *(f32x4*)(lds + s * ROWB + wp * 64 + (k & 3) * 16) = (f32x4){0, 0, 0, 0};
    }

    // ---- weights: af[t][ks][j] = wgt[og*32+lw][ c = ks*16 + hi*8 + j, tap t ]
    //      (wgt row layout: [o][c*9 + t]; lane reads 2x72 contiguous floats)
    bf16x8 af[9][2];
    {
        const float* wrow = wgt + (size_t)(og * 32 + lw) * 288 + hi * 72;
#pragma unroll
        for (int ks = 0; ks < 2; ++ks)
#pragma unroll
            for (int t = 0; t < 9; ++t)
#pragma unroll
                for (int j = 0; j < 8; ++j)
                    af[t][ks][j] = (__bf16)wrow[ks * 144 + j * 9 + t];
    }
    // ---- bias fragment (D-mapped): bvv[r] = bias[og*32 + 4*hi + (r&3)+8*(r>>2)]
    f32x16 bvv;
#pragma unroll
    for (int r = 0; r < 16; ++r)
        bvv[r] = bias[og * 32 + 4 * hi + (r & 3) + 8 * (r >> 2)];

    // ---- r3 staging: wave wid stages channels wid*8..+7 over all 256 w
    auto stage = [&](int row) {
        char* slot = lds + ((row + 1) & 3) * ROWB;
        if (row >= 0 && row < HH) {
            const float* rp = xb + (size_t)row * WW;
#pragma unroll
            for (int wh = 0; wh < 2; ++wh) {
                float2 v[8];
#pragma unroll
                for (int j = 0; j < 8; ++j)
                    v[j] = *(const float2*)(rp + (size_t)(wid * 8 + j) * HW + wh * 128 + 2 * l);
#pragma unroll
                for (int p = 0; p < 2; ++p) {
                    const int w = wh * 128 + 2 * l + p;
                    bf16x8 pk;
#pragma unroll
                    for (int j = 0; j < 8; ++j) pk[j] = (__bf16)(p ? v[j].y : v[j].x);
                    *(bf16x8*)(slot + (w + 1) * 64 + ((wid ^ ((w >> 1) & 3)) << 4)) = pk;
                }
            }
        } else {
#pragma unroll
            for (int wh = 0; wh < 2; ++wh)
#pragma unroll
                for (int p = 0; p < 2; ++p) {
                    const int w = wh * 128 + 2 * l + p;
                    *(f32x4*)(slot + (w + 1) * 64 + ((wid ^ ((w >> 1) & 3)) << 4)) =
                        (f32x4){0, 0, 0, 0};
                }
        }
    };

    stage(h0 - 1); stage(h0); stage(h0 + 1);

    // ---- B-read lane offsets. Entry = wf*128 + t*32 + lw + kw (wp index);
    // swizzle m = ((global_w)>>1)&3 with global_w = entry-1. (wf*128+t*32)>>1
    // is 0 mod 4, and at entry==0 (left pad) global m would be 3 anyway.
    int off6[3][2];
#pragma unroll
    for (int kw = 0; kw < 3; ++kw) {
        const int e = lw + kw;
        const int m = (e == 0) ? 3 : (((e - 1) >> 1) & 3);
#pragma unroll
        for (int ks = 0; ks < 2; ++ks)
            off6[kw][ks] = e * 64 + (((ks * 2 + hi) ^ m) << 4);
    }
    const int halfoff = wf * (128 * 64);         // byte offset of the w-half

    __syncthreads();

    for (int i = 0; i < BH; ++i) {
        const int h  = h0 + i;
        const int nr = h + 2;
        const bool havenext = (i < BH - 1);
        const bool rok2 = havenext && (nr < HH);

        // (1) issue-early: global loads for row h+2 (consumed at step 4)
        float2 v[16];
#pragma unroll
        for (int j = 0; j < 16; ++j) v[j] = make_float2(0.f, 0.f);
        if (rok2) {
            const float* rp = xb + (size_t)nr * WW;
#pragma unroll
            for (int wh = 0; wh < 2; ++wh)
#pragma unroll
                for (int j = 0; j < 8; ++j)
                    v[wh * 8 + j] =
                        *(const float2*)(rp + (size_t)(wid * 8 + j) * HW + wh * 128 + 2 * l);
        }

        // (2) MFMA: 4 w-tiles x 18 k-steps, rows h-1..h+1
        const char* s0 = lds + ((h    ) & 3) * ROWB + halfoff;
        const char* s1 = lds + ((h + 1) & 3) * ROWB + halfoff;
        const char* s2 = lds + ((h + 2) & 3) * ROWB + halfoff;
        f32x16 acc[4];
#pragma unroll
        for (int t = 0; t < 4; ++t) acc[t] = bvv;
#pragma unroll
        for (int t = 0; t < 4; ++t) {
#pragma unroll
            for (int kh = 0; kh < 3; ++kh) {
                const char* s = (kh == 0) ? s0 : (kh == 1) ? s1 : s2;
#pragma unroll
                for (int ks = 0; ks < 2; ++ks)
#pragma unroll
                    for (int kw = 0; kw < 3; ++kw) {
                        bf16x8 bf = *(const bf16x8*)(s + t * 2048 + off6[kw][ks]);
                        acc[t] = __builtin_amdgcn_mfma_f32_32x32x16_bf16(
                            af[kh * 3 + kw][ks], bf, acc[t], 0, 0, 0);
                    }
            }
        }

        // (3) store row h: D col=lw -> w, row=(r&3)+8*(r>>2)+4*hi -> o offset
        float* outb = out + ((size_t)b * OCH + og * 32 + 4 * hi) * HW +
                      (size_t)h * WW + wf * 128 + lw;
#pragma unroll
        for (int t = 0; t < 4; ++t)
#pragma unroll
            for (int r = 0; r < 16; ++r) {
                const int ro = (r & 3) + 8 * (r >> 2);
                outb[(size_t)ro * HW + t * 32] = acc[t][r];
            }

        // (4) write-late: cvt + ds_write row h+2 into slot (h+3)&3
        if (havenext) {
            char* slot = lds + ((nr + 1) & 3) * ROWB;
#pragma unroll
            for (int wh = 0; wh < 2; ++wh)
#pragma unroll
                for (int p = 0; p < 2; ++p) {
                    const int w = wh * 128 + 2 * l + p;
                    bf16x8 pk;
#pragma unroll
                    for (int j = 0; j < 8; ++j)
                        pk[j] = (__bf16)(p ? v[wh * 8 + j].y : v[wh * 8 + j].x);
                    *(bf16x8*)(slot + (w + 1) * 64 + ((wid ^ ((w >> 1) & 3)) << 4)) = pk;
                }
            __syncthreads();
        }
    }
}

extern "C" void kernel_launch(void* const* d_in, const int* in_sizes, int n_in,
                              void* d_out, int out_size, void* d_ws, size_t ws_size,
                              hipStream_t stream) {
    const float* x    = (const float*)d_in[0];
    const float* w    = (const float*)d_in[1];
    const float* bias = (const float*)d_in[2];
    float* out = (float*)d_out;

    hipLaunchKernelGGL(conv_fused_kernel, dim3(512), dim3(256), 0, stream,
                       x, w, bias, out);
}

// Round 9
// 110.396 us; speedup vs baseline: 3.3763x; 1.0460x over previous
//
#include <hip/hip_runtime.h>
#include <hip/hip_bf16.h>

#define CIN 32
#define OCH 64
#define HH  256
#define WW  256
#define HW  (HH * WW)
#define BH  8                 // output rows per block
#define ROWB (258 * 64)       // 16512 B per LDS row-slot

typedef __bf16 bf16x8 __attribute__((ext_vector_type(8)));
typedef float  f32x4  __attribute__((ext_vector_type(4)));
typedef float  f32x16 __attribute__((ext_vector_type(16)));

// Fused 3x3 conv, r8 skeleton + swapped-operand MFMA for vectorized stores.
// mfma(B_x, A_w): D col = o = l&31, row = w = (r&3)+8*(r>>2)+4*(l>>5), so regs
// 4q..4q+3 are 4 consecutive w -> f32x4 stores (16 B/lane, 16 instrs/wave/iter
// vs 64 scalar). Staging loads f32x4 (8 instrs vs 16). G13: vectorize always.
// A/B share the lane mapping (row|col = l&31, k=(l>>5)*8+j) [r7/r8 validated],
// so the swap is argument order only. Block = (b, 8-row h-tile), 4 waves =
// (o-half og, w-half wf). LDS ring/swizzle identical to r8 (B-reads
// conflict-free, enumerated; f32x4 staging writes 4-way on 4 instrs - noise).
__global__ __launch_bounds__(256, 1) void conv_fused_kernel(
        const float* __restrict__ x, const float* __restrict__ wgt,
        const float* __restrict__ bias, float* __restrict__ out) {
    // chunked XCD swizzle: 512 blocks, 64 consecutive nids per XCD.
    const int bid = blockIdx.x;
    const int nid = (bid & 7) * 64 + (bid >> 3);
    const int b   = nid >> 5;                    // 0..15
    const int h0  = (nid & 31) * BH;             // 0..248
    const int tid = threadIdx.x;
    const int l   = tid & 63, wid = tid >> 6;
    const int lw  = l & 31,  hi  = l >> 5;
    const int og  = wid & 1;                     // o-half
    const int wf  = wid >> 1;                    // w-half

    __shared__ __bf16 xs[4][258][CIN];           // 66,048 B ring of 4 row-slots
    char* lds = (char*)&xs[0][0][0];
    const float* xb = x + (size_t)b * CIN * HW;

    // zero the w-pad entries (wp=0 and wp=257) of all 4 slots
    if (tid < 32) {
        const int s = tid >> 3, k = tid & 7;
        const int wp = (k < 4) ? 0 : 257;
        *(f32x4*)(lds + s * ROWB + wp * 64 + (k & 3) * 16) = (f32x4){0, 0, 0, 0};
    }

    // ---- weights: af[t][ks][j] = wgt[og*32+lw][ c = ks*16 + hi*8 + j, tap t ]
    bf16x8 af[9][2];
    {
        const float* wrow = wgt + (size_t)(og * 32 + lw) * 288 + hi * 72;
#pragma unroll
        for (int ks = 0; ks < 2; ++ks)
#pragma unroll
            for (int t = 0; t < 9; ++t)
#pragma unroll
                for (int j = 0; j < 8; ++j)
                    af[t][ks][j] = (__bf16)wrow[ks * 144 + j * 9 + t];
    }
    // bias: transposed D -> every acc reg has the same o = og*32 + lw
    const float bsc = bias[og * 32 + lw];

    // ---- staging: wave wid stages channels wid*8..+7, lane covers w=4l..4l+3
    auto stage = [&](int row) {
        char* slot = lds + ((row + 1) & 3) * ROWB;
        if (row >= 0 && row < HH) {
            const float* rp = xb + (size_t)row * WW;
            f32x4 v[8];
#pragma unroll
            for (int j = 0; j < 8; ++j)
                v[j] = *(const f32x4*)(rp + (size_t)(wid * 8 + j) * HW + 4 * l);
#pragma unroll
            for (int p = 0; p < 4; ++p) {
                const int w = 4 * l + p;
                bf16x8 pk;
#pragma unroll
                for (int j = 0; j < 8; ++j) pk[j] = (__bf16)v[j][p];
                *(bf16x8*)(slot + (w + 1) * 64 + ((wid ^ ((w >> 1) & 3)) << 4)) = pk;
            }
        } else {
#pragma unroll
            for (int p = 0; p < 4; ++p) {
                const int w = 4 * l + p;
                *(f32x4*)(slot + (w + 1) * 64 + ((wid ^ ((w >> 1) & 3)) << 4)) =
                    (f32x4){0, 0, 0, 0};
            }
        }
    };

    stage(h0 - 1); stage(h0); stage(h0 + 1);

    // ---- B-read lane offsets (identical to r8; conflict-free)
    int off6[3][2];
#pragma unroll
    for (int kw = 0; kw < 3; ++kw) {
        const int e = lw + kw;
        const int m = (e == 0) ? 3 : (((e - 1) >> 1) & 3);
#pragma unroll
        for (int ks = 0; ks < 2; ++ks)
            off6[kw][ks] = e * 64 + (((ks * 2 + hi) ^ m) << 4);
    }
    const int halfoff = wf * (128 * 64);

    __syncthreads();

    for (int i = 0; i < BH; ++i) {
        const int h  = h0 + i;
        const int nr = h + 2;
        const bool havenext = (i < BH - 1);
        const bool rok2 = havenext && (nr < HH);

        // (1) issue-early: f32x4 loads for row h+2 (consumed at step 4)
        f32x4 v[8];
#pragma unroll
        for (int j = 0; j < 8; ++j) v[j] = (f32x4){0, 0, 0, 0};
        if (rok2) {
            const float* rp = xb + (size_t)nr * WW;
#pragma unroll
            for (int j = 0; j < 8; ++j)
                v[j] = *(const f32x4*)(rp + (size_t)(wid * 8 + j) * HW + 4 * l);
        }

        // (2) MFMA (swapped operands -> transposed D): rows h-1..h+1
        const char* s0 = lds + ((h    ) & 3) * ROWB + halfoff;
        const char* s1 = lds + ((h + 1) & 3) * ROWB + halfoff;
        const char* s2 = lds + ((h + 2) & 3) * ROWB + halfoff;
        f32x16 acc[4];
#pragma unroll
        for (int t = 0; t < 4; ++t)
#pragma unroll
            for (int r = 0; r < 16; ++r) acc[t][r] = bsc;
#pragma unroll
        for (int t = 0; t < 4; ++t) {
#pragma unroll
            for (int kh = 0; kh < 3; ++kh) {
                const char* s = (kh == 0) ? s0 : (kh == 1) ? s1 : s2;
#pragma unroll
                for (int ks = 0; ks < 2; ++ks)
#pragma unroll
                    for (int kw = 0; kw < 3; ++kw) {
                        bf16x8 bf = *(const bf16x8*)(s + t * 2048 + off6[kw][ks]);
                        acc[t] = __builtin_amdgcn_mfma_f32_32x32x16_bf16(
                            bf, af[kh * 3 + kw][ks], acc[t], 0, 0, 0);
                    }
            }
        }

        // (3) store row h: lane owns o = og*32+lw; regs 4q..4q+3 = w
        //     wf*128 + t*32 + 8q + 4hi + {0..3}  -> f32x4 stores
        float* outb = out + ((size_t)b * OCH + og * 32 + lw) * HW +
                      (size_t)h * WW + wf * 128 + 4 * hi;
#pragma unroll
        for (int t = 0; t < 4; ++t)
#pragma unroll
            for (int q = 0; q < 4; ++q) {
                f32x4 val = { acc[t][4 * q], acc[t][4 * q + 1],
                              acc[t][4 * q + 2], acc[t][4 * q + 3] };
                *(f32x4*)(outb + t * 32 + 8 * q) = val;
            }

        // (4) write-late: cvt + ds_write row h+2 into slot (h+3)&3
        if (havenext) {
            char* slot = lds + ((nr + 1) & 3) * ROWB;
#pragma unroll
            for (int p = 0; p < 4; ++p) {
                const int w = 4 * l + p;
                bf16x8 pk;
#pragma unroll
                for (int j = 0; j < 8; ++j) pk[j] = (__bf16)v[j][p];
                *(bf16x8*)(slot + (w + 1) * 64 + ((wid ^ ((w >> 1) & 3)) << 4)) = pk;
            }
            __syncthreads();
        }
    }
}

extern "C" void kernel_launch(void* const* d_in, const int* in_sizes, int n_in,
                              void* d_out, int out_size, void* d_ws, size_t ws_size,
                              hipStream_t stream) {
    const float* x    = (const float*)d_in[0];
    const float* w    = (const float*)d_in[1];
    const float* bias = (const float*)d_in[2];
    float* out = (float*)d_out;

    hipLaunchKernelGGL(conv_fused_kernel, dim3(512), dim3(256), 0, stream,
                       x, w, bias, out);
}